// Round 1
// baseline (1891.872 us; speedup 1.0000x reference)
//
#include <hip/hip_runtime.h>
#include <cstddef>

#define NROWS 16384
#define NE    8192
#define DD    256
#define TM    64
#define TN    128
#define BK    32

// ---------------------------------------------------------------------------
// k_rowsq: zsq[n] = sum(z[n,:]^2) in numpy pairwise order (256 = 128+128,
// each 128-block via 8 strided accumulators). esq likewise. Also zeroes
// counts + loss accumulator (d_ws is poisoned 0xAA before every call).
// ---------------------------------------------------------------------------
__global__ __launch_bounds__(256) void k_rowsq(
    const float* __restrict__ z, const float* __restrict__ emb,
    float* __restrict__ zsq, float* __restrict__ esq,
    int* __restrict__ counts, float* __restrict__ loss_acc)
{
  const int g = blockIdx.x * 256 + threadIdx.x;   // 0 .. 24575
  if (g < NE) counts[g] = 0;
  if (g == 0) *loss_acc = 0.0f;

  const float* row;
  float* outp;
  if (g < NROWS) { row = z + (size_t)g * DD;            outp = zsq + g; }
  else           { row = emb + (size_t)(g - NROWS) * DD; outp = esq + (g - NROWS); }

  float half_s[2];
#pragma unroll
  for (int h = 0; h < 2; ++h) {
    const float* p = row + h * 128;
    float r[8];
#pragma unroll
    for (int j = 0; j < 8; ++j) {
      float x = p[j];
      float sq = x * x;
      asm volatile("" : "+v"(sq));   // block FMA contraction: np rounds x*x first
      r[j] = sq;
    }
    for (int i = 8; i < 128; i += 8) {
#pragma unroll
      for (int j = 0; j < 8; ++j) {
        float x = p[i + j];
        float sq = x * x;
        asm volatile("" : "+v"(sq));
        r[j] = r[j] + sq;
      }
    }
    half_s[h] = ((r[0] + r[1]) + (r[2] + r[3])) + ((r[4] + r[5]) + (r[6] + r[7]));
  }
  *outp = half_s[0] + half_s[1];
}

// ---------------------------------------------------------------------------
// k_argmin: register-blocked fp32 GEMM computing dot(z_n, e_c), then
// d = fl(fl(zsq+esq) - 2*dot) per the np reference, running argmin with
// lowest-index tie-break. Block: 512 threads, 64 rows x 128 cols, BK=32.
// ---------------------------------------------------------------------------
__global__ __launch_bounds__(512) void k_argmin(
    const float* __restrict__ z, const float* __restrict__ emb,
    const float* __restrict__ zsq, const float* __restrict__ esq,
    int* __restrict__ idx_out, int* __restrict__ counts)
{
  __shared__ float As[BK * TM];     // [k][row]  8 KB
  __shared__ float Bs[BK * TN];     // [k][col] 16 KB
  __shared__ float red_d[TM * 32];  // 8 KB
  __shared__ int   red_i[TM * 32];  // 8 KB

  const int tid = threadIdx.x;
  const int tx = tid & 31;          // col group 0..31
  const int ty = tid >> 5;          // row group 0..15
  const int rowBase = blockIdx.x * TM;
  const int r0 = ty * 4;
  const int c0 = tx * 4;

  // staging mappings
  const int srowA = tid & 63;
  const int skA   = (tid >> 6) << 2;   // 0,4,...,28
  const int scolB = tid & 127;
  const int skB   = (tid >> 7) << 2;   // 0,4,8,12 (plus +16 pass)

  float zr[4];
#pragma unroll
  for (int i = 0; i < 4; ++i) zr[i] = zsq[rowBase + r0 + i];

  float bd[4] = {3.0e38f, 3.0e38f, 3.0e38f, 3.0e38f};
  int   bi[4] = {0, 0, 0, 0};

  for (int t = 0; t < NE; t += TN) {
    float acc[4][4] = {{0.0f}};
    float ev[4];
#pragma unroll
    for (int j = 0; j < 4; ++j) ev[j] = esq[t + c0 + j];

    for (int k0 = 0; k0 < DD; k0 += BK) {
      __syncthreads();
      {
        const float4 av = *(const float4*)(z + (size_t)(rowBase + srowA) * DD + k0 + skA);
        As[(skA + 0) * TM + srowA] = av.x;
        As[(skA + 1) * TM + srowA] = av.y;
        As[(skA + 2) * TM + srowA] = av.z;
        As[(skA + 3) * TM + srowA] = av.w;
      }
#pragma unroll
      for (int h = 0; h < 2; ++h) {
        const int kq = skB + h * 16;
        const float4 bv = *(const float4*)(emb + (size_t)(t + scolB) * DD + k0 + kq);
        Bs[(kq + 0) * TN + scolB] = bv.x;
        Bs[(kq + 1) * TN + scolB] = bv.y;
        Bs[(kq + 2) * TN + scolB] = bv.z;
        Bs[(kq + 3) * TN + scolB] = bv.w;
      }
      __syncthreads();
#pragma unroll
      for (int kk = 0; kk < BK; ++kk) {
        const float4 a = *(const float4*)(As + kk * TM + r0);
        const float4 b = *(const float4*)(Bs + kk * TN + c0);
        acc[0][0] += a.x * b.x; acc[0][1] += a.x * b.y; acc[0][2] += a.x * b.z; acc[0][3] += a.x * b.w;
        acc[1][0] += a.y * b.x; acc[1][1] += a.y * b.y; acc[1][2] += a.y * b.z; acc[1][3] += a.y * b.w;
        acc[2][0] += a.z * b.x; acc[2][1] += a.z * b.y; acc[2][2] += a.z * b.z; acc[2][3] += a.z * b.w;
        acc[3][0] += a.w * b.x; acc[3][1] += a.w * b.y; acc[3][2] += a.w * b.z; acc[3][3] += a.w * b.w;
      }
    }

#pragma unroll
    for (int i = 0; i < 4; ++i) {
#pragma unroll
      for (int j = 0; j < 4; ++j) {
        const float s1 = zr[i] + ev[j];            // fl(zsq + esq), matches np
        const float dv = s1 - 2.0f * acc[i][j];    // fl(s1 - 2*dot); 2*dot exact
        const int col = t + c0 + j;
        if (dv < bd[i]) { bd[i] = dv; bi[i] = col; }  // strict <: first-min wins
      }
    }
  }

#pragma unroll
  for (int i = 0; i < 4; ++i) {
    red_d[(r0 + i) * 32 + tx] = bd[i];
    red_i[(r0 + i) * 32 + tx] = bi[i];
  }
  __syncthreads();
  if (tid < TM) {
    float best = red_d[tid * 32];
    int bidx = red_i[tid * 32];
    for (int x = 1; x < 32; ++x) {
      const float dv = red_d[tid * 32 + x];
      const int ii = red_i[tid * 32 + x];
      if (dv < best || (dv == best && ii < bidx)) { best = dv; bidx = ii; }
    }
    idx_out[rowBase + tid] = bidx;
    atomicAdd(&counts[bidx], 1);
  }
}

// ---------------------------------------------------------------------------
// k_gather: z_q_st output (== gathered embedding rows), one-hot scatter,
// float(index) output, loss partial sums. 4 rows per 256-thread block.
// ---------------------------------------------------------------------------
__global__ __launch_bounds__(256) void k_gather(
    const float* __restrict__ z, const float* __restrict__ emb,
    const int* __restrict__ idxb,
    float* __restrict__ out_zq, float* __restrict__ out_onehot,
    float* __restrict__ out_idx, float* __restrict__ loss_acc)
{
  __shared__ float sred[256];
  const int row = blockIdx.x * 4 + (threadIdx.x >> 6);
  const int lane = threadIdx.x & 63;
  const int idx = idxb[row];
  const int k0 = lane * 4;

  const float4 e  = *(const float4*)(emb + (size_t)idx * DD + k0);
  const float4 zv = *(const float4*)(z + (size_t)row * DD + k0);
  *(float4*)(out_zq + (size_t)row * DD + k0) = e;

  const float dx = e.x - zv.x, dy = e.y - zv.y, dz = e.z - zv.z, dw = e.w - zv.w;
  float local = dx * dx + dy * dy + dz * dz + dw * dw;

  if (lane == 0) {
    out_idx[row] = (float)idx;
    out_onehot[(size_t)row * NE + idx] = 1.0f;
  }

  sred[threadIdx.x] = local;
  __syncthreads();
  for (int s = 128; s > 0; s >>= 1) {
    if (threadIdx.x < s) sred[threadIdx.x] += sred[threadIdx.x + s];
    __syncthreads();
  }
  if (threadIdx.x == 0) atomicAdd(loss_acc, sred[0]);
}

// ---------------------------------------------------------------------------
// k_final: perplexity = exp(-sum(p*log(p+1e-10))), loss = 1.25 * mean.
// ---------------------------------------------------------------------------
__global__ __launch_bounds__(256) void k_final(
    const int* __restrict__ counts, const float* __restrict__ loss_acc,
    float* __restrict__ out_loss, float* __restrict__ out_perp)
{
  __shared__ float sred[256];
  float local = 0.0f;
  for (int e = threadIdx.x; e < NE; e += 256) {
    const float p = (float)counts[e] * (1.0f / 16384.0f);
    local += p * logf(p + 1e-10f);
  }
  sred[threadIdx.x] = local;
  __syncthreads();
  for (int s = 128; s > 0; s >>= 1) {
    if (threadIdx.x < s) sred[threadIdx.x] += sred[threadIdx.x + s];
    __syncthreads();
  }
  if (threadIdx.x == 0) {
    *out_perp = expf(-sred[0]);
    *out_loss = *loss_acc * (1.25f / 4194304.0f);  // (1+beta) * sum / (N*D)
  }
}

// ---------------------------------------------------------------------------
// Output layout (float32, concatenated in reference return order):
//   [0]                loss                       (1)
//   [1 .. 4194304]     z_q_st                     (16384*256)
//   [4194305]          perplexity                 (1)
//   [4194306 ..]       min_encodings one-hot      (16384*8192)
//   [138412034 ..]     min_encoding_indices       (16384, written as float)
// ---------------------------------------------------------------------------
extern "C" void kernel_launch(void* const* d_in, const int* in_sizes, int n_in,
                              void* d_out, int out_size, void* d_ws, size_t ws_size,
                              hipStream_t stream) {
  const float* z   = (const float*)d_in[0];
  const float* emb = (const float*)d_in[1];

  float* out        = (float*)d_out;
  float* out_loss   = out;
  float* out_zq     = out + 1;
  float* out_perp   = out + 4194305;
  float* out_onehot = out + 4194306;
  float* out_idx    = out + 138412034;

  float* zsq      = (float*)d_ws;            // 16384
  float* esq      = zsq + NROWS;             // 8192
  int*   idxb     = (int*)(esq + NE);        // 16384
  int*   counts   = idxb + NROWS;            // 8192
  float* loss_acc = (float*)(counts + NE);   // 1

  // zero the 537 MB one-hot region (re-poisoned 0xAA before every call)
  hipMemsetAsync(out_onehot, 0, (size_t)NROWS * NE * sizeof(float), stream);

  k_rowsq<<<96, 256, 0, stream>>>(z, emb, zsq, esq, counts, loss_acc);
  k_argmin<<<NROWS / TM, 512, 0, stream>>>(z, emb, zsq, esq, idxb, counts);
  k_gather<<<NROWS / 4, 256, 0, stream>>>(z, emb, idxb, out_zq, out_onehot, out_idx, loss_acc);
  k_final<<<1, 256, 0, stream>>>(counts, loss_acc, out_loss, out_perp);
}

// Round 3
// 1547.830 us; speedup vs baseline: 1.2223x; 1.2223x over previous
//
#include <hip/hip_runtime.h>
#include <cstddef>

#define NROWS 16384
#define NE    8192
#define DD    256
#define TM    128
#define TN    128
#define BK    32
#define NCH   4
#define CHW   (NE / NCH)   // 2048 cols per chunk

typedef unsigned long long u64;
typedef float vf4 __attribute__((ext_vector_type(4)));   // native vector for nontemporal builtins

// ---------------------------------------------------------------------------
// k_rowsq: zsq[n] = sum(z[n,:]^2) in numpy pairwise order (256 = 128+128,
// each 128-block via 8 strided accumulators). esq likewise. Also inits
// best[] to u64-max, zeroes counts + loss accumulator.
// ---------------------------------------------------------------------------
__global__ __launch_bounds__(256) void k_rowsq(
    const float* __restrict__ z, const float* __restrict__ emb,
    float* __restrict__ zsq, float* __restrict__ esq,
    u64* __restrict__ best, int* __restrict__ counts,
    float* __restrict__ loss_acc)
{
  const int g = blockIdx.x * 256 + threadIdx.x;   // 0 .. 24575
  if (g < NE) counts[g] = 0;
  if (g < NROWS) best[g] = ~0ull;
  if (g == 0) *loss_acc = 0.0f;

  const float* row;
  float* outp;
  if (g < NROWS) { row = z + (size_t)g * DD;            outp = zsq + g; }
  else           { row = emb + (size_t)(g - NROWS) * DD; outp = esq + (g - NROWS); }

  float half_s[2];
#pragma unroll
  for (int h = 0; h < 2; ++h) {
    const float* p = row + h * 128;
    float r[8];
#pragma unroll
    for (int j = 0; j < 8; ++j) {
      float x = p[j];
      float sq = x * x;
      asm volatile("" : "+v"(sq));   // block FMA contraction: np rounds x*x first
      r[j] = sq;
    }
    for (int i = 8; i < 128; i += 8) {
#pragma unroll
      for (int j = 0; j < 8; ++j) {
        float x = p[i + j];
        float sq = x * x;
        asm volatile("" : "+v"(sq));
        r[j] = r[j] + sq;
      }
    }
    half_s[h] = ((r[0] + r[1]) + (r[2] + r[3])) + ((r[4] + r[5]) + (r[6] + r[7]));
  }
  *outp = half_s[0] + half_s[1];
}

// ---------------------------------------------------------------------------
// k_argmin v2: 128x128 tile, 256 threads, 8x8 micro-tile (rows ty*4+{0..3},
// ty*4+64+{0..3}; cols tx*4+{0..3}, tx*4+64+{0..3}). Columns split into 4
// chunks across blockIdx.y; cross-block reduce via atomicMin on packed
// (float_bits(d) << 32) | col  — d > 0 always, so bits are order-preserving
// and ties resolve to the lowest index, matching np argmin.
// Dot accumulation: sequential k (k0 ascending, kk ascending), FMA — order
// identical to round 1 (which matched the reference exactly).
// ---------------------------------------------------------------------------
__global__ __launch_bounds__(256, 2) void k_argmin(
    const float* __restrict__ z, const float* __restrict__ emb,
    const float* __restrict__ zsq, const float* __restrict__ esq,
    u64* __restrict__ best)
{
  __shared__ float As[BK][TM];          // 16 KB
  __shared__ float Bs[BK][TN];          // 16 KB
  __shared__ u64 red[TM][16];           // 16 KB

  const int tid = threadIdx.x;
  const int tx = tid & 15;
  const int ty = tid >> 4;
  const int tx4 = tx * 4;
  const int ty4 = ty * 4;
  const int R0 = blockIdx.x * TM;
  const int C0 = blockIdx.y * CHW;

  const int srow = tid & 127;
  const int skq  = (tid >> 7) * 16;     // 0 or 16

  float zr[8];
#pragma unroll
  for (int i = 0; i < 4; ++i) {
    zr[i]     = zsq[R0 + ty4 + i];
    zr[4 + i] = zsq[R0 + ty4 + 64 + i];
  }

  u64 bp[8];
#pragma unroll
  for (int i = 0; i < 8; ++i) bp[i] = ~0ull;

  for (int t = 0; t < CHW; t += TN) {
    const int Cb = C0 + t;
    float acc[8][8];
#pragma unroll
    for (int i = 0; i < 8; ++i)
#pragma unroll
      for (int j = 0; j < 8; ++j) acc[i][j] = 0.0f;

    float ev[8];
#pragma unroll
    for (int j = 0; j < 4; ++j) {
      ev[j]     = esq[Cb + tx4 + j];
      ev[4 + j] = esq[Cb + tx4 + 64 + j];
    }

    for (int k0 = 0; k0 < DD; k0 += BK) {
      __syncthreads();
#pragma unroll
      for (int i = 0; i < 4; ++i) {
        const float4 v = *(const float4*)(z + (size_t)(R0 + srow) * DD + k0 + skq + 4 * i);
        As[skq + 4 * i + 0][srow] = v.x;
        As[skq + 4 * i + 1][srow] = v.y;
        As[skq + 4 * i + 2][srow] = v.z;
        As[skq + 4 * i + 3][srow] = v.w;
      }
#pragma unroll
      for (int i = 0; i < 4; ++i) {
        const float4 v = *(const float4*)(emb + (size_t)(Cb + srow) * DD + k0 + skq + 4 * i);
        Bs[skq + 4 * i + 0][srow] = v.x;
        Bs[skq + 4 * i + 1][srow] = v.y;
        Bs[skq + 4 * i + 2][srow] = v.z;
        Bs[skq + 4 * i + 3][srow] = v.w;
      }
      __syncthreads();
#pragma unroll
      for (int kk = 0; kk < BK; ++kk) {
        const float4 a0 = *(const float4*)(&As[kk][ty4]);
        const float4 a1 = *(const float4*)(&As[kk][ty4 + 64]);
        const float4 b0 = *(const float4*)(&Bs[kk][tx4]);
        const float4 b1 = *(const float4*)(&Bs[kk][tx4 + 64]);
        const float av[8] = {a0.x, a0.y, a0.z, a0.w, a1.x, a1.y, a1.z, a1.w};
        const float bv[8] = {b0.x, b0.y, b0.z, b0.w, b1.x, b1.y, b1.z, b1.w};
#pragma unroll
        for (int i = 0; i < 8; ++i)
#pragma unroll
          for (int j = 0; j < 8; ++j)
            acc[i][j] += av[i] * bv[j];
      }
    }

#pragma unroll
    for (int i = 0; i < 8; ++i) {
#pragma unroll
      for (int j = 0; j < 8; ++j) {
        const float s1 = zr[i] + ev[j];           // fl(zsq+esq), matches np
        const float dv = s1 - 2.0f * acc[i][j];   // fl(s1 - 2*dot); 2*dot exact
        const int col = Cb + tx4 + ((j < 4) ? j : 64 + j - 4);
        const u64 p = ((u64)__float_as_uint(dv) << 32) | (unsigned)col;
        if (p < bp[i]) bp[i] = p;
      }
    }
  }

#pragma unroll
  for (int i = 0; i < 8; ++i) {
    const int lr = (i < 4) ? (ty4 + i) : (ty4 + 64 + i - 4);
    red[lr][tx] = bp[i];
  }
  __syncthreads();
  if (tid < TM) {
    u64 m = red[tid][0];
#pragma unroll
    for (int x = 1; x < 16; ++x) {
      const u64 v = red[tid][x];
      if (v < m) m = v;
    }
    atomicMin(&best[R0 + tid], m);
  }
}

// ---------------------------------------------------------------------------
// k_emit: one block per row. Writes the full one-hot row (zeros + the 1.0),
// gathers z_q, emits float(index), accumulates loss, bumps counts.
// Replaces the separate 537 MB memset pass.
// ---------------------------------------------------------------------------
__global__ __launch_bounds__(256) void k_emit(
    const float* __restrict__ z, const float* __restrict__ emb,
    const u64* __restrict__ best,
    float* __restrict__ out_zq, float* __restrict__ out_onehot,
    float* __restrict__ out_idx, float* __restrict__ loss_acc,
    int* __restrict__ counts)
{
  const int row = blockIdx.x;
  const int tid = threadIdx.x;
  const int idx = (int)(unsigned)(best[row] & 0xffffffffull);

  float* orow = out_onehot + (size_t)row * NE;
#pragma unroll
  for (int it = 0; it < 8; ++it) {
    const int base = it * 1024 + tid * 4;
    vf4 v;
    v.x = (idx == base + 0) ? 1.0f : 0.0f;
    v.y = (idx == base + 1) ? 1.0f : 0.0f;
    v.z = (idx == base + 2) ? 1.0f : 0.0f;
    v.w = (idx == base + 3) ? 1.0f : 0.0f;
    __builtin_nontemporal_store(v, (vf4*)(orow + base));
  }

  if (tid < 64) {
    const int k0 = tid * 4;
    const float4 e  = *(const float4*)(emb + (size_t)idx * DD + k0);
    const float4 zv = *(const float4*)(z + (size_t)row * DD + k0);
    *(float4*)(out_zq + (size_t)row * DD + k0) = e;
    const float dx = e.x - zv.x, dy = e.y - zv.y, dz = e.z - zv.z, dw = e.w - zv.w;
    float local = dx * dx + dy * dy + dz * dz + dw * dw;
#pragma unroll
    for (int off = 32; off > 0; off >>= 1) local += __shfl_down(local, off, 64);
    if (tid == 0) {
      atomicAdd(loss_acc, local);
      out_idx[row] = (float)idx;
      atomicAdd(&counts[idx], 1);
    }
  }
}

// ---------------------------------------------------------------------------
// k_final: perplexity = exp(-sum(p*log(p+1e-10))), loss = 1.25 * mean.
// ---------------------------------------------------------------------------
__global__ __launch_bounds__(256) void k_final(
    const int* __restrict__ counts, const float* __restrict__ loss_acc,
    float* __restrict__ out_loss, float* __restrict__ out_perp)
{
  __shared__ float sred[256];
  float local = 0.0f;
  for (int e = threadIdx.x; e < NE; e += 256) {
    const float p = (float)counts[e] * (1.0f / 16384.0f);
    local += p * logf(p + 1e-10f);
  }
  sred[threadIdx.x] = local;
  __syncthreads();
  for (int s = 128; s > 0; s >>= 1) {
    if (threadIdx.x < s) sred[threadIdx.x] += sred[threadIdx.x + s];
    __syncthreads();
  }
  if (threadIdx.x == 0) {
    *out_perp = expf(-sred[0]);
    *out_loss = *loss_acc * (1.25f / 4194304.0f);  // (1+beta) * sum / (N*D)
  }
}

// ---------------------------------------------------------------------------
// Output layout (float32, concatenated in reference return order):
//   [0]                loss                       (1)
//   [1 .. 4194304]     z_q_st                     (16384*256)
//   [4194305]          perplexity                 (1)
//   [4194306 ..]       min_encodings one-hot      (16384*8192)
//   [138412034 ..]     min_encoding_indices       (16384, written as float)
// ---------------------------------------------------------------------------
extern "C" void kernel_launch(void* const* d_in, const int* in_sizes, int n_in,
                              void* d_out, int out_size, void* d_ws, size_t ws_size,
                              hipStream_t stream) {
  const float* z   = (const float*)d_in[0];
  const float* emb = (const float*)d_in[1];

  float* out        = (float*)d_out;
  float* out_loss   = out;
  float* out_zq     = out + 1;
  float* out_perp   = out + 4194305;
  float* out_onehot = out + 4194306;
  float* out_idx    = out + 138412034;

  float* zsq      = (float*)d_ws;            // 16384 f
  float* esq      = zsq + NROWS;             // 8192 f
  u64*   best     = (u64*)(esq + NE);        // 16384 u64 (8B-aligned: offset 96 KB)
  int*   counts   = (int*)(best + NROWS);    // 8192 int
  float* loss_acc = (float*)(counts + NE);   // 1 f

  k_rowsq<<<96, 256, 0, stream>>>(z, emb, zsq, esq, best, counts, loss_acc);
  k_argmin<<<dim3(NROWS / TM, NCH), 256, 0, stream>>>(z, emb, zsq, esq, best);
  k_emit<<<NROWS, 256, 0, stream>>>(z, emb, best, out_zq, out_onehot, out_idx,
                                    loss_acc, counts);
  k_final<<<1, 256, 0, stream>>>(counts, loss_acc, out_loss, out_perp);
}